// Round 5
// baseline (74.910 us; speedup 1.0000x reference)
//
#include <hip/hip_runtime.h>
#include <math.h>

// Problem constants (fixed by the reference)
#define B_ 512
#define K_ 1024
#define D_ 256
#define EPS_ 1e-6f

typedef unsigned short u16;
using bf16x8 = __attribute__((ext_vector_type(8))) short;  // 8 bf16 = 4 VGPRs
using f32x4  = __attribute__((ext_vector_type(4))) float;  // MFMA C/D

// ---- workspace layout (u16 element offsets for the bf16 hi/lo arrays) ----
#define XHI_OFF 0
#define XLO_OFF (512 * 256)
#define PHI_OFF (2 * 512 * 256)
#define PLO_OFF (PHI_OFF + 1024 * 256)
#define AHI_OFF (PLO_OFF + 1024 * 256)
#define ALO_OFF (AHI_OFF + 1024 * 256)
#define BF16_TOTAL (ALO_OFF + 1024 * 256)      // 1,310,720 u16 = 2,621,440 B
#define SCAL_BYTE_OFF (BF16_TOTAL * 2)
// scalar floats at SCAL_BYTE_OFF: x2[512], p2[1024], a2[1024], pa[1024]

// round-to-nearest-even fp32 -> bf16, and the exact residual split
__device__ inline u16 bf16_rn(float v) {
    unsigned u = __float_as_uint(v);
    unsigned r = u + 0x7FFFu + ((u >> 16) & 1u);
    return (u16)(r >> 16);
}
__device__ inline void split2(float v, u16& h, u16& l) {
    h = bf16_rn(v);
    float hf = __uint_as_float(((unsigned)h) << 16);
    l = bf16_rn(v - hf);   // v - hf is exact
}

// ---------------------------------------------------------------------------
// Kernel 1: fp32 -> (hi, lo) bf16 conversion + per-row scalars.
// One wave per row; lane l owns elements [4l, 4l+4). Rows 0..511 = x,
// rows 512..1535 = (p, a) pairs. Grid 384 x 256 threads (4 rows/block).
// ---------------------------------------------------------------------------
__global__ __launch_bounds__(256) void prep_kernel(
    const float* __restrict__ x, const float* __restrict__ p,
    const float* __restrict__ a, u16* __restrict__ wsu,
    float* __restrict__ scal)
{
    const int lane = threadIdx.x & 63;
    const int rid  = blockIdx.x * 4 + (threadIdx.x >> 6);
    float* x2 = scal;
    float* p2 = scal + 512;
    float* a2 = scal + 512 + 1024;
    float* pa = scal + 512 + 2048;

    if (rid < 512) {
        const float4 v = *(const float4*)&x[rid * D_ + lane * 4];
        ushort4 h, l;
        split2(v.x, h.x, l.x); split2(v.y, h.y, l.y);
        split2(v.z, h.z, l.z); split2(v.w, h.w, l.w);
        *(ushort4*)&wsu[XHI_OFF + rid * D_ + lane * 4] = h;
        *(ushort4*)&wsu[XLO_OFF + rid * D_ + lane * 4] = l;
        float s = v.x * v.x + v.y * v.y + v.z * v.z + v.w * v.w;
#pragma unroll
        for (int off = 32; off; off >>= 1) s += __shfl_down(s, off);
        if (lane == 0) x2[rid] = s;
    } else {
        const int k = rid - 512;
        const float4 vp = *(const float4*)&p[k * D_ + lane * 4];
        const float4 va = *(const float4*)&a[k * D_ + lane * 4];
        ushort4 hp, lp, ha, la;
        split2(vp.x, hp.x, lp.x); split2(vp.y, hp.y, lp.y);
        split2(vp.z, hp.z, lp.z); split2(vp.w, hp.w, lp.w);
        split2(va.x, ha.x, la.x); split2(va.y, ha.y, la.y);
        split2(va.z, ha.z, la.z); split2(va.w, ha.w, la.w);
        *(ushort4*)&wsu[PHI_OFF + k * D_ + lane * 4] = hp;
        *(ushort4*)&wsu[PLO_OFF + k * D_ + lane * 4] = lp;
        *(ushort4*)&wsu[AHI_OFF + k * D_ + lane * 4] = ha;
        *(ushort4*)&wsu[ALO_OFF + k * D_ + lane * 4] = la;
        float sp = vp.x * vp.x + vp.y * vp.y + vp.z * vp.z + vp.w * vp.w;
        float sa = va.x * va.x + va.y * va.y + va.z * va.z + va.w * va.w;
        float sx = vp.x * va.x + vp.y * va.y + vp.z * va.z + vp.w * va.w;
#pragma unroll
        for (int off = 32; off; off >>= 1) {
            sp += __shfl_down(sp, off);
            sa += __shfl_down(sa, off);
            sx += __shfl_down(sx, off);
        }
        if (lane == 0) { p2[k] = sp; a2[k] = sa; pa[k] = sx; }
    }
}

// Ganea hyperbolic MLR logit from the 6 scalars (z never materialized).
__device__ inline float hyp_logit(float dt, float xa, float x2,
                                  float p2, float a2, float pav) {
    const float beta  = 1.0f - p2;
    const float alpha = 1.0f + x2 - 2.0f * dt;
    const float den   = 1.0f - 2.0f * dt + p2 * x2;
    const float rg    = 1.0f / (den + EPS_);
    const float z2    = (alpha * alpha * p2 - 2.0f * alpha * beta * dt
                         + beta * beta * x2) * rg * rg;
    const float za    = beta * (beta * xa - alpha * pav) * rg;
    const float na    = beta * sqrtf(a2);
    const float lam   = 2.0f / (beta + EPS_);
    const float arg   = 2.0f * za / ((1.0f - z2) * na + EPS_);
    return lam * na * asinhf(arg);
}

// ---------------------------------------------------------------------------
// Kernel 2: dual GEMM via mfma_f32_16x16x32_bf16, 3-pass hi/lo split,
// fragments straight from L2 (no LDS).
// Per wave: 16 b-rows x 16 k-cols, full D -> 2048 waves, 512 blocks of 256
// (2 blocks/CU, 2 waves/SIMD) to hide L2/HBM latency (round-4 fix: was
// 1 wave/SIMD, fully latency-exposed).
// A-frag: X[b0+(lane&15)][quad*8+j]; B-frag: P/A[kc][quad*8+j].
// C/D: col(k)=lane&15, row(b)=quad*4+reg (verified by round-4 pass @3e-5).
// ---------------------------------------------------------------------------
__global__ __launch_bounds__(256, 2) void mfma_kernel(
    const u16* __restrict__ wsu, const float* __restrict__ scal,
    float* __restrict__ out)
{
    const int lane = threadIdx.x & 63;
    const int w    = threadIdx.x >> 6;
    const int l15  = lane & 15;
    const int quad = lane >> 4;
    const int b0   = blockIdx.y * 16;
    const int kc   = blockIdx.x * 64 + w * 16 + l15;   // this lane's k column

    const float* x2s = scal;
    const float* p2s = scal + 512;
    const float* a2s = scal + 512 + 1024;
    const float* pas = scal + 512 + 2048;

    const int arow = b0 + l15;
    const int dq   = quad * 8;

    const u16* xh = wsu + XHI_OFF + arow * D_ + dq;
    const u16* xl = wsu + XLO_OFF + arow * D_ + dq;
    const u16* ph = wsu + PHI_OFF + kc * D_ + dq;
    const u16* pl = wsu + PLO_OFF + kc * D_ + dq;
    const u16* ah = wsu + AHI_OFF + kc * D_ + dq;
    const u16* al = wsu + ALO_OFF + kc * D_ + dq;

    f32x4 accP = {0.f, 0.f, 0.f, 0.f};
    f32x4 accA = {0.f, 0.f, 0.f, 0.f};

#pragma unroll
    for (int dc = 0; dc < 8; ++dc) {
        const int d = dc * 32;
        bf16x8 Ah = *(const bf16x8*)(xh + d);
        bf16x8 Al = *(const bf16x8*)(xl + d);
        bf16x8 Ph = *(const bf16x8*)(ph + d);
        bf16x8 Pl = *(const bf16x8*)(pl + d);
        bf16x8 Bh = *(const bf16x8*)(ah + d);
        bf16x8 Bl = *(const bf16x8*)(al + d);

        accP = __builtin_amdgcn_mfma_f32_16x16x32_bf16(Ah, Ph, accP, 0, 0, 0);
        accP = __builtin_amdgcn_mfma_f32_16x16x32_bf16(Ah, Pl, accP, 0, 0, 0);
        accP = __builtin_amdgcn_mfma_f32_16x16x32_bf16(Al, Ph, accP, 0, 0, 0);

        accA = __builtin_amdgcn_mfma_f32_16x16x32_bf16(Ah, Bh, accA, 0, 0, 0);
        accA = __builtin_amdgcn_mfma_f32_16x16x32_bf16(Ah, Bl, accA, 0, 0, 0);
        accA = __builtin_amdgcn_mfma_f32_16x16x32_bf16(Al, Bh, accA, 0, 0, 0);
    }

    const float p2v = p2s[kc], a2v = a2s[kc], pav = pas[kc];
#pragma unroll
    for (int r = 0; r < 4; ++r) {
        const int b = b0 + quad * 4 + r;
        out[b * K_ + kc] = hyp_logit(accP[r], accA[r], x2s[b], p2v, a2v, pav);
    }
}

extern "C" void kernel_launch(void* const* d_in, const int* in_sizes, int n_in,
                              void* d_out, int out_size, void* d_ws, size_t ws_size,
                              hipStream_t stream) {
    const float* x = (const float*)d_in[0];  // [512, 256]
    const float* p = (const float*)d_in[1];  // [1024, 256]
    const float* a = (const float*)d_in[2];  // [1024, 256]
    float* out = (float*)d_out;              // [512, 1024]
    u16* wsu   = (u16*)d_ws;
    float* scal = (float*)((char*)d_ws + SCAL_BYTE_OFF);

    prep_kernel<<<384, 256, 0, stream>>>(x, p, a, wsu, scal);
    dim3 g2(16, 32);  // 512 blocks: 16b x 64k each -> 2 blocks/CU, 2 waves/SIMD
    mfma_kernel<<<g2, 256, 0, stream>>>(wsu, scal, out);
}